// Round 1
// baseline (4408.326 us; speedup 1.0000x reference)
//
#include <hip/hip_runtime.h>

#define TPB 256

// ---------------- degree / normalization ----------------

__global__ __launch_bounds__(TPB) void init_deg_kernel(float* __restrict__ deg, int n) {
    int i = blockIdx.x * TPB + threadIdx.x;
    if (i < n) deg[i] = 1.0f;  // self-loop contributes 1 to every node's in-degree
}

__global__ __launch_bounds__(TPB) void count_deg_kernel(const int* __restrict__ dst,
                                                        float* __restrict__ deg, int e) {
    int i = blockIdx.x * TPB + threadIdx.x;
    if (i < e) atomicAdd(&deg[dst[i]], 1.0f);
}

__global__ __launch_bounds__(TPB) void dinv_kernel(float* __restrict__ deg, int n) {
    int i = blockIdx.x * TPB + threadIdx.x;
    if (i < n) deg[i] = 1.0f / sqrtf(deg[i]);  // deg >= 1 always (self-loop)
}

// ---------------- dense transform: H = (relu?)(X) @ W ----------------
// X: [nrows,128] fp32, W: [128,M] fp32 row-major, H: [nrows,M]
// W staged in LDS; each thread owns 4 consecutive output cols for one row-slot.

template <int M, bool RELU>
__global__ __launch_bounds__(TPB) void gemm_kernel(const float* __restrict__ X,
                                                   const float* __restrict__ W,
                                                   float* __restrict__ H, int nrows) {
    constexpr int CG  = M / 4;       // col-groups of 4 per row
    constexpr int RPB = TPB / CG;    // rows per block iteration (8 for M=128, 16 for M=64)
    __shared__ float Wl[128 * M];
    __shared__ float Xl[RPB * 128];

    for (int i = threadIdx.x; i < 128 * M / 4; i += TPB)
        ((float4*)Wl)[i] = ((const float4*)W)[i];

    const int cg = threadIdx.x % CG;
    const int rs = threadIdx.x / CG;

    for (long row0 = (long)blockIdx.x * RPB; row0 < nrows; row0 += (long)gridDim.x * RPB) {
        // stage RPB rows of X into LDS (coalesced float4), fused ReLU for layer 2
        for (int f = threadIdx.x; f < RPB * 32; f += TPB) {
            int  r   = f >> 5;
            int  c4  = f & 31;
            long row = row0 + r;
            float4 v = make_float4(0.f, 0.f, 0.f, 0.f);
            if (row < nrows) v = ((const float4*)(X + row * 128))[c4];
            if (RELU) {
                v.x = fmaxf(v.x, 0.f); v.y = fmaxf(v.y, 0.f);
                v.z = fmaxf(v.z, 0.f); v.w = fmaxf(v.w, 0.f);
            }
            ((float4*)Xl)[f] = v;
        }
        __syncthreads();

        long row = row0 + rs;
        if (row < nrows) {
            float4 acc = make_float4(0.f, 0.f, 0.f, 0.f);
            const float* xr = Xl + rs * 128;
#pragma unroll
            for (int k = 0; k < 128; ++k) {
                float  xv = xr[k];                          // LDS broadcast within row-group
                float4 wv = ((const float4*)Wl)[k * CG + cg];  // conflict-free b128
                acc.x += xv * wv.x; acc.y += xv * wv.y;
                acc.z += xv * wv.z; acc.w += xv * wv.w;
            }
            ((float4*)(H + row * M))[cg] = acc;
        }
        __syncthreads();  // protect Xl before next staging pass
    }
}

// ---------------- aggregation ----------------
// out[i,:] = b + dinv[i]^2 * h[i,:]   (self-loop + bias init; also zero-inits vs 0xAA poison)

template <int M>
__global__ __launch_bounds__(TPB) void agg_init_kernel(const float* __restrict__ h,
                                                       const float* __restrict__ dinv,
                                                       const float* __restrict__ bias,
                                                       float* __restrict__ out, int n) {
    constexpr int C4 = M / 4;
    long t   = (long)blockIdx.x * TPB + threadIdx.x;
    long tot = (long)n * C4;
    if (t >= tot) return;
    int i  = (int)(t / C4);
    int c4 = (int)(t % C4);
    float w  = dinv[i] * dinv[i];
    float4 hv = ((const float4*)(h + (long)i * M))[c4];
    float4 bv = ((const float4*)bias)[c4];
    float4 o;
    o.x = bv.x + w * hv.x; o.y = bv.y + w * hv.y;
    o.z = bv.z + w * hv.z; o.w = bv.w + w * hv.w;
    ((float4*)(out + (long)i * M))[c4] = o;
}

// out[dst,:] += dinv[src]*dinv[dst] * h[src,:]  -- one thread per (edge, 4 channels)

template <int M>
__global__ __launch_bounds__(TPB) void agg_edges_kernel(const float* __restrict__ h,
                                                        const int* __restrict__ src,
                                                        const int* __restrict__ dst,
                                                        const float* __restrict__ dinv,
                                                        float* __restrict__ out, long nwork) {
    constexpr int CP = M / 4;  // float4 chunks per edge
    long t = (long)blockIdx.x * TPB + threadIdx.x;
    if (t >= nwork) return;
    long e  = t / CP;
    int  c4 = (int)(t % CP);
    int  s = src[e], d = dst[e];
    float w = dinv[s] * dinv[d];
    float4 hv = ((const float4*)(h + (long)s * M))[c4];
    float* op = out + (long)d * M + c4 * 4;
    atomicAdd(op + 0, hv.x * w);
    atomicAdd(op + 1, hv.y * w);
    atomicAdd(op + 2, hv.z * w);
    atomicAdd(op + 3, hv.w * w);
}

// ---------------- launcher ----------------

extern "C" void kernel_launch(void* const* d_in, const int* in_sizes, int n_in,
                              void* d_out, int out_size, void* d_ws, size_t ws_size,
                              hipStream_t stream) {
    const float* x  = (const float*)d_in[0];
    const int*   ei = (const int*)d_in[1];   // int32 on the wire (JAX x64 disabled)
    const float* W1 = (const float*)d_in[2];
    const float* b1 = (const float*)d_in[3];
    const float* W2 = (const float*)d_in[4];
    const float* b2 = (const float*)d_in[5];
    float* out = (float*)d_out;

    const int N = in_sizes[0] / 128;   // 100000
    const int E = in_sizes[1] / 2;     // 1600000
    const int* srcv = ei;
    const int* dstv = ei + E;

    // workspace layout (fp32): dinv[N] | h1[N*128] | out1[N*128]; h2 overlays h1
    float* dinv = (float*)d_ws;
    float* h1   = dinv + (((size_t)N + 1023) & ~(size_t)1023);
    float* out1 = h1 + (size_t)N * 128;
    float* h2   = h1;  // h1 dead once out1 (agg of conv1) is complete

    const int nb  = (N + TPB - 1) / TPB;
    const int eb  = (E + TPB - 1) / TPB;

    // normalization
    init_deg_kernel<<<nb, TPB, 0, stream>>>(dinv, N);
    count_deg_kernel<<<eb, TPB, 0, stream>>>(dstv, dinv, E);
    dinv_kernel<<<nb, TPB, 0, stream>>>(dinv, N);

    // layer 1: h1 = x @ W1 ; out1 = scatter(h1) + b1  (relu fused into gemm2 load)
    gemm_kernel<128, false><<<(N + 7) / 8, TPB, 0, stream>>>(x, W1, h1, N);
    {
        long tot = (long)N * 32;
        agg_init_kernel<128><<<(int)((tot + TPB - 1) / TPB), TPB, 0, stream>>>(h1, dinv, b1, out1, N);
        long nwork = (long)E * 32;
        agg_edges_kernel<128><<<(int)((nwork + TPB - 1) / TPB), TPB, 0, stream>>>(h1, srcv, dstv, dinv, out1, nwork);
    }

    // layer 2: h2 = relu(out1) @ W2 ; out = scatter(h2) + b2
    gemm_kernel<64, true><<<(N + 15) / 16, TPB, 0, stream>>>(out1, W2, h2, N);
    {
        long tot = (long)N * 16;
        agg_init_kernel<64><<<(int)((tot + TPB - 1) / TPB), TPB, 0, stream>>>(h2, dinv, b2, out, N);
        long nwork = (long)E * 16;
        agg_edges_kernel<64><<<(int)((nwork + TPB - 1) / TPB), TPB, 0, stream>>>(h2, srcv, dstv, dinv, out, nwork);
    }
}

// Round 2
// 775.514 us; speedup vs baseline: 5.6844x; 5.6844x over previous
//
#include <hip/hip_runtime.h>

#define TPB 256
#define CHUNK 1024  // elements per scan block (256 threads x 4)

// ---------------- degree count (int) ----------------

__global__ __launch_bounds__(TPB) void count_deg_kernel(const int* __restrict__ dst,
                                                        int* __restrict__ cnt, int e) {
    int i = blockIdx.x * TPB + threadIdx.x;
    if (i < e) atomicAdd(&cnt[dst[i]], 1);
}

__global__ __launch_bounds__(TPB) void dinv_kernel(const int* __restrict__ cnt,
                                                   float* __restrict__ dinv, int n) {
    int i = blockIdx.x * TPB + threadIdx.x;
    if (i < n) dinv[i] = rsqrtf((float)(cnt[i] + 1));  // +1 self-loop
}

// ---------------- two-level exclusive scan: counts -> row_ptr ----------------

__global__ __launch_bounds__(256) void scanA_kernel(const int* __restrict__ cnt,
                                                    int* __restrict__ row_ptr,
                                                    int* __restrict__ chunk_sums, int n) {
    __shared__ int ls[256];
    const int t    = threadIdx.x;
    const int base = blockIdx.x * CHUNK;
    const int idx  = base + t * 4;
    int4 v = make_int4(0, 0, 0, 0);
    if (idx + 3 < n) v = *(const int4*)(cnt + idx);
    else {
        if (idx + 0 < n) v.x = cnt[idx + 0];
        if (idx + 1 < n) v.y = cnt[idx + 1];
        if (idx + 2 < n) v.z = cnt[idx + 2];
        if (idx + 3 < n) v.w = cnt[idx + 3];
    }
    int s0 = v.x, s1 = s0 + v.y, s2 = s1 + v.z, s3 = s2 + v.w;
    ls[t] = s3;
    __syncthreads();
    for (int off = 1; off < 256; off <<= 1) {
        int xv = (t >= off) ? ls[t - off] : 0;
        __syncthreads();
        ls[t] += xv;
        __syncthreads();
    }
    int excl = (t == 0) ? 0 : ls[t - 1];
    if (idx + 0 < n) row_ptr[idx + 0] = excl;
    if (idx + 1 < n) row_ptr[idx + 1] = excl + s0;
    if (idx + 2 < n) row_ptr[idx + 2] = excl + s1;
    if (idx + 3 < n) row_ptr[idx + 3] = excl + s2;
    if (t == 255) chunk_sums[blockIdx.x] = ls[255];
}

__global__ __launch_bounds__(256) void scanB_kernel(int* __restrict__ chunk_sums, int nch) {
    __shared__ int ls[256];
    const int t = threadIdx.x;
    ls[t] = (t < nch) ? chunk_sums[t] : 0;
    __syncthreads();
    for (int off = 1; off < 256; off <<= 1) {
        int xv = (t >= off) ? ls[t - off] : 0;
        __syncthreads();
        ls[t] += xv;
        __syncthreads();
    }
    if (t < nch) chunk_sums[t] = (t == 0) ? 0 : ls[t - 1];  // exclusive
}

__global__ __launch_bounds__(256) void scanC_kernel(int* __restrict__ row_ptr,
                                                    int* __restrict__ fill_off,
                                                    const int* __restrict__ chunk_sums,
                                                    int n, int e_total) {
    const int base = blockIdx.x * CHUNK;
    const int off  = chunk_sums[blockIdx.x];
    for (int k = threadIdx.x; k < CHUNK; k += 256) {
        int i = base + k;
        if (i < n) {
            int rv = row_ptr[i] + off;
            row_ptr[i]  = rv;
            fill_off[i] = rv;
        }
    }
    if (blockIdx.x == 0 && threadIdx.x == 0) row_ptr[n] = e_total;
}

__global__ __launch_bounds__(TPB) void fill_csr_kernel(const int* __restrict__ src,
                                                       const int* __restrict__ dst,
                                                       int* __restrict__ fill_off,
                                                       int* __restrict__ csr_src, int e) {
    int i = blockIdx.x * TPB + threadIdx.x;
    if (i < e) {
        int p = atomicAdd(&fill_off[dst[i]], 1);
        csr_src[p] = src[i];
    }
}

// ---------------- dense transform: HS = dinv[row] * (relu?)(X) @ W ----------------

template <int M, bool RELU>
__global__ __launch_bounds__(TPB) void gemm_kernel(const float* __restrict__ X,
                                                   const float* __restrict__ W,
                                                   const float* __restrict__ dinv,
                                                   float* __restrict__ H, int nrows) {
    constexpr int CG  = M / 4;       // col-groups of 4 per row
    constexpr int RPB = TPB / CG;    // rows per block iteration
    __shared__ float Wl[128 * M];
    __shared__ float Xl[RPB * 128];

    for (int i = threadIdx.x; i < 128 * M / 4; i += TPB)
        ((float4*)Wl)[i] = ((const float4*)W)[i];

    const int cg = threadIdx.x % CG;
    const int rs = threadIdx.x / CG;

    for (long row0 = (long)blockIdx.x * RPB; row0 < nrows; row0 += (long)gridDim.x * RPB) {
        for (int f = threadIdx.x; f < RPB * 32; f += TPB) {
            int  r   = f >> 5;
            int  c4  = f & 31;
            long row = row0 + r;
            float4 v = make_float4(0.f, 0.f, 0.f, 0.f);
            if (row < nrows) v = ((const float4*)(X + row * 128))[c4];
            if (RELU) {
                v.x = fmaxf(v.x, 0.f); v.y = fmaxf(v.y, 0.f);
                v.z = fmaxf(v.z, 0.f); v.w = fmaxf(v.w, 0.f);
            }
            ((float4*)Xl)[f] = v;
        }
        __syncthreads();

        long row = row0 + rs;
        if (row < nrows) {
            float4 acc = make_float4(0.f, 0.f, 0.f, 0.f);
            const float* xr = Xl + rs * 128;
#pragma unroll
            for (int k = 0; k < 128; ++k) {
                float  xv = xr[k];
                float4 wv = ((const float4*)Wl)[k * CG + cg];
                acc.x += xv * wv.x; acc.y += xv * wv.y;
                acc.z += xv * wv.z; acc.w += xv * wv.w;
            }
            float dv = dinv[row];
            acc.x *= dv; acc.y *= dv; acc.z *= dv; acc.w *= dv;
            ((float4*)(H + row * M))[cg] = acc;
        }
        __syncthreads();
    }
}

// ---------------- pull aggregation: out[d] = b + dinv[d]*(hs[d] + sum hs[src]) ----------------
// one wave per node; lane owns M/64 floats

template <int M>
__global__ __launch_bounds__(TPB) void agg_pull_kernel(const float* __restrict__ hs,
                                                       const int* __restrict__ csr_src,
                                                       const int* __restrict__ row_ptr,
                                                       const float* __restrict__ dinv,
                                                       const float* __restrict__ bias,
                                                       float* __restrict__ out, int n) {
    const int node = blockIdx.x * (TPB / 64) + (threadIdx.x >> 6);
    const int lane = threadIdx.x & 63;
    if (node >= n) return;
    const int beg = row_ptr[node];
    const int end = row_ptr[node + 1];

    if constexpr (M == 128) {
        const float2* hp = (const float2*)hs;
        float2 acc = hp[(long)node * 64 + lane];  // self-loop term hs[d]
        int s = (beg < end) ? csr_src[beg] : 0;
        for (int e = beg; e < end; ++e) {
            int sn = (e + 1 < end) ? csr_src[e + 1] : 0;  // prefetch next index
            float2 v = hp[(long)s * 64 + lane];
            acc.x += v.x; acc.y += v.y;
            s = sn;
        }
        float  di = dinv[node];
        float2 bv = ((const float2*)bias)[lane];
        float2 o  = make_float2(bv.x + di * acc.x, bv.y + di * acc.y);
        ((float2*)out)[(long)node * 64 + lane] = o;
    } else {  // M == 64
        float acc = hs[(long)node * 64 + lane];
        int s = (beg < end) ? csr_src[beg] : 0;
        for (int e = beg; e < end; ++e) {
            int sn = (e + 1 < end) ? csr_src[e + 1] : 0;
            acc += hs[(long)s * 64 + lane];
            s = sn;
        }
        float di = dinv[node];
        out[(long)node * 64 + lane] = bias[lane] + di * acc;
    }
}

// ---------------- launcher ----------------

extern "C" void kernel_launch(void* const* d_in, const int* in_sizes, int n_in,
                              void* d_out, int out_size, void* d_ws, size_t ws_size,
                              hipStream_t stream) {
    const float* x  = (const float*)d_in[0];
    const int*   ei = (const int*)d_in[1];   // int32 on the wire
    const float* W1 = (const float*)d_in[2];
    const float* b1 = (const float*)d_in[3];
    const float* W2 = (const float*)d_in[4];
    const float* b2 = (const float*)d_in[5];
    float* out = (float*)d_out;

    const int N = in_sizes[0] / 128;   // 100000
    const int E = in_sizes[1] / 2;     // 1600000
    const int* srcv = ei;
    const int* dstv = ei + E;

    const int NCH = (N + CHUNK - 1) / CHUNK;  // 98 <= 256

    // workspace layout
    char* p = (char*)d_ws;
    int*   cnt        = (int*)p;            p += ((size_t)N + 64) * 4;   // also reused as fill_off
    int*   row_ptr    = (int*)p;            p += ((size_t)N + 64) * 4;
    int*   chunk_sums = (int*)p;            p += 1024;
    int*   csr_src    = (int*)p;            p += (size_t)E * 4;
    float* dinv       = (float*)p;          p += ((size_t)N + 64) * 4;
    float* h1         = (float*)p;          p += (size_t)N * 128 * 4;
    float* out1       = (float*)p;          /* p += N*128*4 */
    int*   fill_off   = cnt;                // cnt dead after scanA + dinv
    float* h2         = h1;                 // h1 dead once out1 complete

    const int nb = (N + TPB - 1) / TPB;
    const int eb = (E + TPB - 1) / TPB;

    // ---- normalization + CSR build (reused by both layers) ----
    hipMemsetAsync(cnt, 0, (size_t)N * 4, stream);
    count_deg_kernel<<<eb, TPB, 0, stream>>>(dstv, cnt, E);
    dinv_kernel<<<nb, TPB, 0, stream>>>(cnt, dinv, N);
    scanA_kernel<<<NCH, 256, 0, stream>>>(cnt, row_ptr, chunk_sums, N);
    scanB_kernel<<<1, 256, 0, stream>>>(chunk_sums, NCH);
    scanC_kernel<<<NCH, 256, 0, stream>>>(row_ptr, fill_off, chunk_sums, N, E);
    fill_csr_kernel<<<eb, TPB, 0, stream>>>(srcv, dstv, fill_off, csr_src, E);

    // ---- layer 1 ----
    gemm_kernel<128, false><<<(N + 7) / 8, TPB, 0, stream>>>(x, W1, dinv, h1, N);
    agg_pull_kernel<128><<<(N * 64 + TPB - 1) / TPB, TPB, 0, stream>>>(h1, csr_src, row_ptr, dinv, b1, out1, N);

    // ---- layer 2 ----
    gemm_kernel<64, true><<<(N + 15) / 16, TPB, 0, stream>>>(out1, W2, dinv, h2, N);
    agg_pull_kernel<64><<<(N * 64 + TPB - 1) / TPB, TPB, 0, stream>>>(h2, csr_src, row_ptr, dinv, b2, out, N);
}

// Round 3
// 574.629 us; speedup vs baseline: 7.6716x; 1.3496x over previous
//
#include <hip/hip_runtime.h>

#define TPB 256
#define CHUNK 1024  // elements per scan block (256 threads x 4)

// ---------------- degree count (int) ----------------

__global__ __launch_bounds__(TPB) void count_deg_kernel(const int* __restrict__ dst,
                                                        int* __restrict__ cnt, int e) {
    int i = blockIdx.x * TPB + threadIdx.x;
    if (i < e) atomicAdd(&cnt[dst[i]], 1);
}

__global__ __launch_bounds__(TPB) void dinv_kernel(const int* __restrict__ cnt,
                                                   float* __restrict__ dinv, int n) {
    int i = blockIdx.x * TPB + threadIdx.x;
    if (i < n) dinv[i] = rsqrtf((float)(cnt[i] + 1));  // +1 self-loop
}

// ---------------- two-level exclusive scan: counts -> row_ptr ----------------

__global__ __launch_bounds__(256) void scanA_kernel(const int* __restrict__ cnt,
                                                    int* __restrict__ row_ptr,
                                                    int* __restrict__ chunk_sums, int n) {
    __shared__ int ls[256];
    const int t    = threadIdx.x;
    const int base = blockIdx.x * CHUNK;
    const int idx  = base + t * 4;
    int4 v = make_int4(0, 0, 0, 0);
    if (idx + 3 < n) v = *(const int4*)(cnt + idx);
    else {
        if (idx + 0 < n) v.x = cnt[idx + 0];
        if (idx + 1 < n) v.y = cnt[idx + 1];
        if (idx + 2 < n) v.z = cnt[idx + 2];
        if (idx + 3 < n) v.w = cnt[idx + 3];
    }
    int s0 = v.x, s1 = s0 + v.y, s2 = s1 + v.z, s3 = s2 + v.w;
    ls[t] = s3;
    __syncthreads();
    for (int off = 1; off < 256; off <<= 1) {
        int xv = (t >= off) ? ls[t - off] : 0;
        __syncthreads();
        ls[t] += xv;
        __syncthreads();
    }
    int excl = (t == 0) ? 0 : ls[t - 1];
    if (idx + 0 < n) row_ptr[idx + 0] = excl;
    if (idx + 1 < n) row_ptr[idx + 1] = excl + s0;
    if (idx + 2 < n) row_ptr[idx + 2] = excl + s1;
    if (idx + 3 < n) row_ptr[idx + 3] = excl + s2;
    if (t == 255) chunk_sums[blockIdx.x] = ls[255];
}

__global__ __launch_bounds__(256) void scanB_kernel(int* __restrict__ chunk_sums, int nch) {
    __shared__ int ls[256];
    const int t = threadIdx.x;
    ls[t] = (t < nch) ? chunk_sums[t] : 0;
    __syncthreads();
    for (int off = 1; off < 256; off <<= 1) {
        int xv = (t >= off) ? ls[t - off] : 0;
        __syncthreads();
        ls[t] += xv;
        __syncthreads();
    }
    if (t < nch) chunk_sums[t] = (t == 0) ? 0 : ls[t - 1];  // exclusive
}

__global__ __launch_bounds__(256) void scanC_kernel(int* __restrict__ row_ptr,
                                                    int* __restrict__ fill_off,
                                                    const int* __restrict__ chunk_sums,
                                                    int n, int e_total) {
    const int base = blockIdx.x * CHUNK;
    const int off  = chunk_sums[blockIdx.x];
    for (int k = threadIdx.x; k < CHUNK; k += 256) {
        int i = base + k;
        if (i < n) {
            int rv = row_ptr[i] + off;
            row_ptr[i]  = rv;
            fill_off[i] = rv;
        }
    }
    if (blockIdx.x == 0 && threadIdx.x == 0) row_ptr[n] = e_total;
}

__global__ __launch_bounds__(TPB) void fill_csr_kernel(const int* __restrict__ src,
                                                       const int* __restrict__ dst,
                                                       int* __restrict__ fill_off,
                                                       int* __restrict__ csr_src, int e) {
    int i = blockIdx.x * TPB + threadIdx.x;
    if (i < e) {
        int p = atomicAdd(&fill_off[dst[i]], 1);
        csr_src[p] = src[i];
    }
}

// ---------------- dense transform: HS = dinv[row] * (relu?)(X) @ W ----------------
// Register-blocked: each thread computes R=4 rows x 4 cols; one ds_read_b128 of W
// feeds 16 FMAs -> VALU-bound instead of LDS-bound.

template <int M, bool RELU>
__global__ __launch_bounds__(TPB) void gemm_kernel(const float* __restrict__ X,
                                                   const float* __restrict__ W,
                                                   const float* __restrict__ dinv,
                                                   float* __restrict__ H, int nrows) {
    constexpr int CG  = M / 4;        // col-groups of 4 (32 for M=128, 16 for M=64)
    constexpr int RG  = TPB / CG;     // row-groups per block (8 / 16)
    constexpr int R   = 4;            // rows per thread
    constexpr int RPB = RG * R;       // rows per block iter (32 / 64)
    __shared__ float Wl[128 * M];     // 64 KB / 32 KB
    __shared__ float Xl[RPB * 128];   // 16 KB / 32 KB

    for (int i = threadIdx.x; i < 128 * M / 4; i += TPB)
        ((float4*)Wl)[i] = ((const float4*)W)[i];

    const int cg = threadIdx.x % CG;
    const int rg = threadIdx.x / CG;

    for (long row0 = (long)blockIdx.x * RPB; row0 < nrows; row0 += (long)gridDim.x * RPB) {
        // stage RPB rows of X into LDS (coalesced float4), fused ReLU for layer 2
        for (int f = threadIdx.x; f < RPB * 32; f += TPB) {
            int  r   = f >> 5;
            int  c4  = f & 31;
            long row = row0 + r;
            float4 v = make_float4(0.f, 0.f, 0.f, 0.f);
            if (row < nrows) v = ((const float4*)(X + row * 128))[c4];
            if (RELU) {
                v.x = fmaxf(v.x, 0.f); v.y = fmaxf(v.y, 0.f);
                v.z = fmaxf(v.z, 0.f); v.w = fmaxf(v.w, 0.f);
            }
            ((float4*)Xl)[f] = v;
        }
        __syncthreads();

        float4 acc[R];
#pragma unroll
        for (int r = 0; r < R; ++r) acc[r] = make_float4(0.f, 0.f, 0.f, 0.f);
        const float* xb = Xl + (rg * R) * 128;

#pragma unroll 8
        for (int k = 0; k < 128; ++k) {
            float4 wv = ((const float4*)Wl)[k * CG + cg];  // conflict-free b128
#pragma unroll
            for (int r = 0; r < R; ++r) {
                float xv = xb[r * 128 + k];                // LDS broadcast
                acc[r].x += xv * wv.x; acc[r].y += xv * wv.y;
                acc[r].z += xv * wv.z; acc[r].w += xv * wv.w;
            }
        }

#pragma unroll
        for (int r = 0; r < R; ++r) {
            long row = row0 + rg * R + r;
            if (row < nrows) {
                float dv = dinv[row];
                float4 o = make_float4(acc[r].x * dv, acc[r].y * dv,
                                       acc[r].z * dv, acc[r].w * dv);
                ((float4*)(H + row * M))[cg] = o;
            }
        }
        __syncthreads();
    }
}

// ---------------- pull aggregation: out[d] = b + dinv[d]*(hs[d] + sum hs[src]) ----------------
// one wave per node; neighbor indices loaded lane-parallel (coalesced) then
// broadcast via shfl; 4-way unrolled independent gathers for MLP.

template <int M>
__global__ __launch_bounds__(TPB) void agg_pull_kernel(const float* __restrict__ hs,
                                                       const int* __restrict__ csr_src,
                                                       const int* __restrict__ row_ptr,
                                                       const float* __restrict__ dinv,
                                                       const float* __restrict__ bias,
                                                       float* __restrict__ out, int n) {
    const int node = blockIdx.x * (TPB / 64) + (threadIdx.x >> 6);
    const int lane = threadIdx.x & 63;
    if (node >= n) return;
    const int beg = row_ptr[node];
    const int end = row_ptr[node + 1];

    if constexpr (M == 128) {
        const float2* hp = (const float2*)hs;
        float2 a0 = hp[(long)node * 64 + lane];  // self-loop term
        float2 a1 = make_float2(0.f, 0.f);
        float2 a2 = make_float2(0.f, 0.f);
        float2 a3 = make_float2(0.f, 0.f);
        for (int base = beg; base < end; base += 64) {
            int m = end - base; if (m > 64) m = 64;
            int idx = (lane < m) ? csr_src[base + lane] : 0;  // coalesced index load
            int j = 0;
            for (; j + 3 < m; j += 4) {
                int s0 = __shfl(idx, j);
                int s1 = __shfl(idx, j + 1);
                int s2 = __shfl(idx, j + 2);
                int s3 = __shfl(idx, j + 3);
                float2 v0 = hp[(long)s0 * 64 + lane];
                float2 v1 = hp[(long)s1 * 64 + lane];
                float2 v2 = hp[(long)s2 * 64 + lane];
                float2 v3 = hp[(long)s3 * 64 + lane];
                a0.x += v0.x; a0.y += v0.y;
                a1.x += v1.x; a1.y += v1.y;
                a2.x += v2.x; a2.y += v2.y;
                a3.x += v3.x; a3.y += v3.y;
            }
            for (; j < m; ++j) {
                int s0 = __shfl(idx, j);
                float2 v0 = hp[(long)s0 * 64 + lane];
                a0.x += v0.x; a0.y += v0.y;
            }
        }
        float  di = dinv[node];
        float2 bv = ((const float2*)bias)[lane];
        float2 o;
        o.x = bv.x + di * ((a0.x + a1.x) + (a2.x + a3.x));
        o.y = bv.y + di * ((a0.y + a1.y) + (a2.y + a3.y));
        ((float2*)out)[(long)node * 64 + lane] = o;
    } else {  // M == 64
        float a0 = hs[(long)node * 64 + lane];
        float a1 = 0.f, a2 = 0.f, a3 = 0.f;
        for (int base = beg; base < end; base += 64) {
            int m = end - base; if (m > 64) m = 64;
            int idx = (lane < m) ? csr_src[base + lane] : 0;
            int j = 0;
            for (; j + 3 < m; j += 4) {
                int s0 = __shfl(idx, j);
                int s1 = __shfl(idx, j + 1);
                int s2 = __shfl(idx, j + 2);
                int s3 = __shfl(idx, j + 3);
                a0 += hs[(long)s0 * 64 + lane];
                a1 += hs[(long)s1 * 64 + lane];
                a2 += hs[(long)s2 * 64 + lane];
                a3 += hs[(long)s3 * 64 + lane];
            }
            for (; j < m; ++j) {
                int s0 = __shfl(idx, j);
                a0 += hs[(long)s0 * 64 + lane];
            }
        }
        float di = dinv[node];
        out[(long)node * 64 + lane] = bias[lane] + di * ((a0 + a1) + (a2 + a3));
    }
}

// ---------------- launcher ----------------

extern "C" void kernel_launch(void* const* d_in, const int* in_sizes, int n_in,
                              void* d_out, int out_size, void* d_ws, size_t ws_size,
                              hipStream_t stream) {
    const float* x  = (const float*)d_in[0];
    const int*   ei = (const int*)d_in[1];   // int32 on the wire
    const float* W1 = (const float*)d_in[2];
    const float* b1 = (const float*)d_in[3];
    const float* W2 = (const float*)d_in[4];
    const float* b2 = (const float*)d_in[5];
    float* out = (float*)d_out;

    const int N = in_sizes[0] / 128;   // 100000
    const int E = in_sizes[1] / 2;     // 1600000
    const int* srcv = ei;
    const int* dstv = ei + E;

    const int NCH = (N + CHUNK - 1) / CHUNK;  // 98 <= 256

    // workspace layout
    char* p = (char*)d_ws;
    int*   cnt        = (int*)p;            p += ((size_t)N + 64) * 4;   // reused as fill_off
    int*   row_ptr    = (int*)p;            p += ((size_t)N + 64) * 4;
    int*   chunk_sums = (int*)p;            p += 1024;
    int*   csr_src    = (int*)p;            p += (size_t)E * 4;
    float* dinv       = (float*)p;          p += ((size_t)N + 64) * 4;
    float* h1         = (float*)p;          p += (size_t)N * 128 * 4;
    float* out1       = (float*)p;          /* p += N*128*4 */
    int*   fill_off   = cnt;                // cnt dead after scanA + dinv
    float* h2         = h1;                 // h1 dead once out1 complete

    const int nb = (N + TPB - 1) / TPB;
    const int eb = (E + TPB - 1) / TPB;

    // ---- normalization + CSR build (reused by both layers) ----
    hipMemsetAsync(cnt, 0, (size_t)N * 4, stream);
    count_deg_kernel<<<eb, TPB, 0, stream>>>(dstv, cnt, E);
    dinv_kernel<<<nb, TPB, 0, stream>>>(cnt, dinv, N);
    scanA_kernel<<<NCH, 256, 0, stream>>>(cnt, row_ptr, chunk_sums, N);
    scanB_kernel<<<1, 256, 0, stream>>>(chunk_sums, NCH);
    scanC_kernel<<<NCH, 256, 0, stream>>>(row_ptr, fill_off, chunk_sums, N, E);
    fill_csr_kernel<<<eb, TPB, 0, stream>>>(srcv, dstv, fill_off, csr_src, E);

    // ---- layer 1 ----
    gemm_kernel<128, false><<<(N + 31) / 32, TPB, 0, stream>>>(x, W1, dinv, h1, N);
    agg_pull_kernel<128><<<(N + 3) / 4, TPB, 0, stream>>>(h1, csr_src, row_ptr, dinv, b1, out1, N);

    // ---- layer 2 ----
    gemm_kernel<64, true><<<(N + 63) / 64, TPB, 0, stream>>>(out1, W2, dinv, h2, N);
    agg_pull_kernel<64><<<(N + 3) / 4, TPB, 0, stream>>>(h2, csr_src, row_ptr, dinv, b2, out, N);
}